// Round 4
// baseline (2516.376 us; speedup 1.0000x reference)
//
#include <hip/hip_runtime.h>
#include <hip/hip_fp16.h>
#include <cstdint>
#include <cstddef>

// GCNII: h0 = relu(x@W_in + b_in); 8x { s = .9*Ahat@h + .1*h0; h = relu(s @ Wl) };
// out = h@W_out + b_out.  Ahat = D^-1/2 (A + I) D^-1/2 (deg over targets, +1 self loop).
// Activations fp16, GEMM accum fp32, weights fp32.
// CSR = 4B src only; norm recomputed as dinv[src]*dinv[dst] (broadcast L2 reads).
// Aggregation + layer GEMM fused: LDS A-tile (half2, transposed-pair layout).

#define HID 128

// ---------------- preprocessing ----------------

__global__ void k_hist(const int* __restrict__ col, int E, int* __restrict__ cnt) {
  int e = blockIdx.x * blockDim.x + threadIdx.x;
  if (e < E) atomicAdd(&cnt[col[e]], 1);
}

__global__ void k_dinv(const int* __restrict__ cnt, float* __restrict__ dinv, int N) {
  int i = blockIdx.x * blockDim.x + threadIdx.x;
  if (i < N) dinv[i] = rsqrtf((float)cnt[i] + 1.0f);  // +1 self loop
}

__global__ __launch_bounds__(256) void k_blocksum(const int* __restrict__ cnt,
                                                  int* __restrict__ bsum, int N) {
  __shared__ int s[256];
  int t = threadIdx.x;
  int i = blockIdx.x * 256 + t;
  s[t] = (i < N) ? cnt[i] : 0;
  __syncthreads();
  for (int off = 128; off > 0; off >>= 1) {
    if (t < off) s[t] += s[t + off];
    __syncthreads();
  }
  if (t == 0) bsum[blockIdx.x] = s[0];
}

__global__ __launch_bounds__(512) void k_scan_bsum(const int* __restrict__ bsum,
                                                   int* __restrict__ bofs, int nb) {
  __shared__ int s[512];
  __shared__ int carry;
  int t = threadIdx.x;
  if (t == 0) carry = 0;
  __syncthreads();
  for (int base = 0; base < nb; base += 512) {
    int i = base + t;
    int v = (i < nb) ? bsum[i] : 0;
    s[t] = v;
    __syncthreads();
    for (int off = 1; off < 512; off <<= 1) {
      int a = (t >= off) ? s[t - off] : 0;
      __syncthreads();
      s[t] += a;
      __syncthreads();
    }
    if (i < nb) bofs[i] = carry + s[t] - v;
    __syncthreads();
    if (t == 0) carry += s[511];
    __syncthreads();
  }
}

__global__ __launch_bounds__(256) void k_scan_write(const int* __restrict__ cnt,
                                                    const int* __restrict__ bofs,
                                                    int* __restrict__ row_ptr, int N) {
  __shared__ int s[256];
  int t = threadIdx.x;
  int i = blockIdx.x * 256 + t;
  int v = (i < N) ? cnt[i] : 0;
  s[t] = v;
  __syncthreads();
  for (int off = 1; off < 256; off <<= 1) {
    int a = (t >= off) ? s[t - off] : 0;
    __syncthreads();
    s[t] += a;
    __syncthreads();
  }
  int excl = bofs[blockIdx.x] + s[t] - v;
  if (i < N) row_ptr[i] = excl;
  if (i == N - 1) row_ptr[N] = excl + v;
}

__global__ void k_fill(const int* __restrict__ row, const int* __restrict__ col, int E,
                       const int* __restrict__ row_ptr, int* __restrict__ fill,
                       int* __restrict__ csr_src) {
  int e = blockIdx.x * blockDim.x + threadIdx.x;
  if (e >= E) return;
  int r = row[e], c = col[e];
  int p = row_ptr[c] + atomicAdd(&fill[c], 1);
  csr_src[p] = r;
}

// ---------------- fused layer: s = .9*Ahat@h + .1*x0 ; hout = relu(s @ W) ----------------
// 128 nodes per block, 256 threads.  Phase 1: wave w aggregates nodes w*32..w*32+31 into
// LDS asTp[64][132] (half2: dims (2k,2k+1) x local row, 528B row stride -> aligned b128).
// Phase 2: 8x8 register-tile GEMM vs W (fp32, staged BK=16), relu, fp16 out.

__global__ __launch_bounds__(256) void k_fused_layer(
    const __half* __restrict__ h, const __half* __restrict__ x0h,
    const float* __restrict__ dinv, const int* __restrict__ row_ptr,
    const int* __restrict__ csr_src, const float* __restrict__ W,
    __half* __restrict__ hout, int N) {
  __shared__ __half2 asTp[64][132];
  __shared__ float Bs[16][128];
  int tid = threadIdx.x;
  int wid = tid >> 6, lane = tid & 63;
  int row0 = blockIdx.x * 128;

  // ---- phase 1: aggregate 32 nodes per wave ----
  for (int i = 0; i < 32; ++i) {
    int r = wid * 32 + i;
    int node = row0 + r;
    float sx = 0.0f, sy = 0.0f;
    if (node < N) {
      int beg = row_ptr[node], end = row_ptr[node + 1];
      float di = dinv[node];
      float2 f0 = __half22float2(((const __half2*)(h + (size_t)node * HID))[lane]);
      float ax = di * f0.x;   // acc = di*h[node] + sum dinv[s]*h[s]; support = .9*di*acc + .1*x0
      float ay = di * f0.y;
      int j = beg;
      for (; j + 4 <= end; j += 4) {
        int s0 = csr_src[j], s1 = csr_src[j + 1], s2 = csr_src[j + 2], s3 = csr_src[j + 3];
        float w0 = dinv[s0], w1 = dinv[s1], w2 = dinv[s2], w3 = dinv[s3];
        __half2 a0 = ((const __half2*)(h + (size_t)s0 * HID))[lane];
        __half2 a1 = ((const __half2*)(h + (size_t)s1 * HID))[lane];
        __half2 a2 = ((const __half2*)(h + (size_t)s2 * HID))[lane];
        __half2 a3 = ((const __half2*)(h + (size_t)s3 * HID))[lane];
        float2 f;
        f = __half22float2(a0); ax = fmaf(w0, f.x, ax); ay = fmaf(w0, f.y, ay);
        f = __half22float2(a1); ax = fmaf(w1, f.x, ax); ay = fmaf(w1, f.y, ay);
        f = __half22float2(a2); ax = fmaf(w2, f.x, ax); ay = fmaf(w2, f.y, ay);
        f = __half22float2(a3); ax = fmaf(w3, f.x, ax); ay = fmaf(w3, f.y, ay);
      }
      for (; j < end; ++j) {
        int s = csr_src[j];
        float w = dinv[s];
        float2 f = __half22float2(((const __half2*)(h + (size_t)s * HID))[lane]);
        ax = fmaf(w, f.x, ax);
        ay = fmaf(w, f.y, ay);
      }
      float2 xv = __half22float2(((const __half2*)(x0h + (size_t)node * HID))[lane]);
      float s9 = 0.9f * di;
      sx = s9 * ax + 0.1f * xv.x;
      sy = s9 * ay + 0.1f * xv.y;
    }
    asTp[lane][r] = __floats2half2_rn(sx, sy);
  }
  __syncthreads();

  // ---- phase 2: C = relu(S @ W), S from LDS ----
  int tx = tid & 15, ty = tid >> 4;
  float acc[8][8];
#pragma unroll
  for (int m = 0; m < 8; ++m)
#pragma unroll
    for (int n = 0; n < 8; ++n) acc[m][n] = 0.0f;

  int bk = tid >> 4;            // 0..15
  int bc = (tid & 15) * 4;      // 0..60

  for (int kk = 0; kk < 128; kk += 16) {
    *(float4*)&Bs[bk][bc] = *(const float4*)(W + (size_t)(kk + bk) * HID + bc);
    *(float4*)&Bs[bk][64 + bc] = *(const float4*)(W + (size_t)(kk + bk) * HID + 64 + bc);
    __syncthreads();
#pragma unroll
    for (int k2 = 0; k2 < 8; ++k2) {
      int kd2 = (kk >> 1) + k2;  // asTp row: dims (2*kd2, 2*kd2+1)
      const __half2* ap = &asTp[kd2][ty * 8];
      float4 r0 = *(const float4*)ap;
      float4 r1 = *(const float4*)(ap + 4);
      float a0[8], a1[8];
      const __half2* hp0 = (const __half2*)&r0;
      const __half2* hp1 = (const __half2*)&r1;
#pragma unroll
      for (int m = 0; m < 4; ++m) {
        float2 f = __half22float2(hp0[m]);
        a0[m] = f.x; a1[m] = f.y;
        float2 g = __half22float2(hp1[m]);
        a0[4 + m] = g.x; a1[4 + m] = g.y;
      }
      float b0[8], b1[8];
      int k0 = 2 * k2, k1 = 2 * k2 + 1;
      *(float4*)&b0[0] = *(const float4*)&Bs[k0][tx * 4];
      *(float4*)&b0[4] = *(const float4*)&Bs[k0][64 + tx * 4];
      *(float4*)&b1[0] = *(const float4*)&Bs[k1][tx * 4];
      *(float4*)&b1[4] = *(const float4*)&Bs[k1][64 + tx * 4];
#pragma unroll
      for (int m = 0; m < 8; ++m)
#pragma unroll
        for (int n = 0; n < 8; ++n) {
          acc[m][n] = fmaf(a0[m], b0[n], acc[m][n]);
          acc[m][n] = fmaf(a1[m], b1[n], acc[m][n]);
        }
    }
    __syncthreads();
  }

#pragma unroll
  for (int m = 0; m < 8; ++m) {
    int r = row0 + ty * 8 + m;
    if (r >= N) continue;
    float v[8];
#pragma unroll
    for (int n = 0; n < 8; ++n) v[n] = fmaxf(acc[m][n], 0.0f);
    __half2 h01 = __floats2half2_rn(v[0], v[1]);
    __half2 h23 = __floats2half2_rn(v[2], v[3]);
    __half2 h45 = __floats2half2_rn(v[4], v[5]);
    __half2 h67 = __floats2half2_rn(v[6], v[7]);
    float2 pk0, pk1;
    ((__half2*)&pk0)[0] = h01; ((__half2*)&pk0)[1] = h23;
    ((__half2*)&pk1)[0] = h45; ((__half2*)&pk1)[1] = h67;
    *(float2*)(hout + (size_t)r * HID + tx * 4) = pk0;
    *(float2*)(hout + (size_t)r * HID + 64 + tx * 4) = pk1;
  }
}

// ---------------- standalone GEMM (input / output projection) ----------------

template <int NC, bool RELU, bool BIAS, bool AHALF, bool OHALF>
__global__ __launch_bounds__(256) void k_gemm(const void* __restrict__ Av,
                                              const float* __restrict__ B,
                                              const float* __restrict__ bias,
                                              void* __restrict__ Cv, int M) {
  constexpr int TN = NC / 16;  // 8 (NC=128) or 4 (NC=64)
  __shared__ float As[16][128];
  __shared__ float Bs[16][NC];
  int tid = threadIdx.x;
  int tx = tid & 15, ty = tid >> 4;
  int row0 = blockIdx.x * 128;

  float acc[8][TN];
#pragma unroll
  for (int m = 0; m < 8; ++m)
#pragma unroll
    for (int n = 0; n < TN; ++n) acc[m][n] = 0.0f;

  int la_row = tid >> 1;        // 0..127
  int la_k = (tid & 1) * 8;     // 0 or 8
  int ar = row0 + la_row;
  int bk = tid >> 4;            // 0..15
  int bc = (tid & 15) * 4;      // 0..60

  for (int kk = 0; kk < 128; kk += 16) {
    float f[8];
    if (ar < M) {
      if (AHALF) {
        const __half* Ah = (const __half*)Av;
        float4 raw = *(const float4*)(Ah + (size_t)ar * 128 + kk + la_k);
        const __half2* hp = (const __half2*)&raw;
#pragma unroll
        for (int i = 0; i < 4; ++i) {
          float2 t2 = __half22float2(hp[i]);
          f[2 * i] = t2.x;
          f[2 * i + 1] = t2.y;
        }
      } else {
        const float* Af = (const float*)Av;
        *(float4*)&f[0] = *(const float4*)(Af + (size_t)ar * 128 + kk + la_k);
        *(float4*)&f[4] = *(const float4*)(Af + (size_t)ar * 128 + kk + la_k + 4);
      }
    } else {
#pragma unroll
      for (int i = 0; i < 8; ++i) f[i] = 0.0f;
    }
#pragma unroll
    for (int i = 0; i < 8; ++i) As[la_k + i][la_row] = f[i];
    *(float4*)&Bs[bk][bc] = *(const float4*)(B + (size_t)(kk + bk) * NC + bc);
    if (TN == 8)
      *(float4*)&Bs[bk][64 + bc] = *(const float4*)(B + (size_t)(kk + bk) * NC + 64 + bc);
    __syncthreads();
#pragma unroll
    for (int k = 0; k < 16; ++k) {
      float a[8], b[TN];
      *(float4*)&a[0] = *(const float4*)&As[k][ty * 8];
      *(float4*)&a[4] = *(const float4*)&As[k][ty * 8 + 4];
      *(float4*)&b[0] = *(const float4*)&Bs[k][tx * 4];
      if (TN == 8) *(float4*)&b[4] = *(const float4*)&Bs[k][64 + tx * 4];
#pragma unroll
      for (int m = 0; m < 8; ++m)
#pragma unroll
        for (int n = 0; n < TN; ++n) acc[m][n] = fmaf(a[m], b[n], acc[m][n]);
    }
    __syncthreads();
  }

#pragma unroll
  for (int m = 0; m < 8; ++m) {
    int r = row0 + ty * 8 + m;
    if (r >= M) continue;
    float v[TN];
#pragma unroll
    for (int n = 0; n < TN; ++n) {
      int c = (n < 4) ? (tx * 4 + n) : (64 + tx * 4 + n - 4);
      v[n] = acc[m][n];
      if (BIAS) v[n] += bias[c];
      if (RELU) v[n] = fmaxf(v[n], 0.0f);
    }
    if (OHALF) {
      __half* Ch = (__half*)Cv;
      __half2 h01 = __floats2half2_rn(v[0], v[1]);
      __half2 h23 = __floats2half2_rn(v[2], v[3]);
      float2 pk0;
      ((__half2*)&pk0)[0] = h01;
      ((__half2*)&pk0)[1] = h23;
      *(float2*)(Ch + (size_t)r * NC + tx * 4) = pk0;
      if (TN == 8) {
        __half2 h45 = __floats2half2_rn(v[4], v[5]);
        __half2 h67 = __floats2half2_rn(v[6], v[7]);
        float2 pk1;
        ((__half2*)&pk1)[0] = h45;
        ((__half2*)&pk1)[1] = h67;
        *(float2*)(Ch + (size_t)r * NC + 64 + tx * 4) = pk1;
      }
    } else {
      float* Cf = (float*)Cv;
      *(float4*)(Cf + (size_t)r * NC + tx * 4) = *(float4*)&v[0];
      if (TN == 8) *(float4*)(Cf + (size_t)r * NC + 64 + tx * 4) = *(float4*)&v[4];
    }
  }
}

// ---------------- launch ----------------

extern "C" void kernel_launch(void* const* d_in, const int* in_sizes, int n_in,
                              void* d_out, int out_size, void* d_ws, size_t ws_size,
                              hipStream_t stream) {
  const float* x     = (const float*)d_in[0];
  const int*   ei    = (const int*)d_in[1];
  const float* W_in  = (const float*)d_in[2];
  const float* b_in  = (const float*)d_in[3];
  const float* Wc    = (const float*)d_in[4];
  const float* W_out = (const float*)d_in[5];
  const float* b_out = (const float*)d_in[6];
  float* out = (float*)d_out;

  const int N = in_sizes[0] / HID;          // 100000
  const int E = in_sizes[1] / 2;            // 1600000
  const int L = in_sizes[4] / (HID * HID);  // 8
  const int nb = (N + 255) / 256;           // scan blocks
  const int* row = ei;       // sources
  const int* col = ei + E;   // targets

  char* p = (char*)d_ws;
  auto alloc = [&](size_t bytes) {
    char* q = p;
    p += (bytes + 255) & ~(size_t)255;
    return q;
  };
  int*    cnt     = (int*)alloc((size_t)N * 4);
  int*    row_ptr = (int*)alloc((size_t)(N + 1) * 4);
  int*    fill    = (int*)alloc((size_t)N * 4);
  int*    bsum    = (int*)alloc((size_t)nb * 4);
  int*    bofs    = (int*)alloc((size_t)nb * 4);
  float*  dinv    = (float*)alloc((size_t)N * 4);
  int*    csr_src = (int*)alloc((size_t)E * 4);
  __half* x0h     = (__half*)alloc((size_t)N * HID * 2);
  __half* hA      = (__half*)alloc((size_t)N * HID * 2);
  __half* hB      = (__half*)alloc((size_t)N * HID * 2);
  (void)ws_size; (void)n_in; (void)out_size;

  hipMemsetAsync(cnt, 0, (size_t)N * 4, stream);
  hipMemsetAsync(fill, 0, (size_t)N * 4, stream);

  k_hist<<<(E + 255) / 256, 256, 0, stream>>>(col, E, cnt);
  k_dinv<<<(N + 255) / 256, 256, 0, stream>>>(cnt, dinv, N);
  k_blocksum<<<nb, 256, 0, stream>>>(cnt, bsum, N);
  k_scan_bsum<<<1, 512, 0, stream>>>(bsum, bofs, nb);
  k_scan_write<<<nb, 256, 0, stream>>>(cnt, bofs, row_ptr, N);
  k_fill<<<(E + 255) / 256, 256, 0, stream>>>(row, col, E, row_ptr, fill, csr_src);

  int ggrid = (N + 127) / 128;
  // input projection -> x0h (fp16)
  k_gemm<128, true, true, false, true><<<ggrid, 256, 0, stream>>>(x, W_in, b_in, x0h, N);

  const __half* hin = x0h;
  __half* bufs[2] = {hA, hB};
  for (int l = 0; l < L; ++l) {
    __half* ho = bufs[l & 1];
    k_fused_layer<<<ggrid, 256, 0, stream>>>(hin, x0h, dinv, row_ptr, csr_src,
                                             Wc + (size_t)l * HID * HID, ho, N);
    hin = ho;
  }
  // output projection (A fp16, out fp32)
  k_gemm<64, false, true, true, false><<<ggrid, 256, 0, stream>>>(hin, W_out, b_out,
                                                                  out, N);
}

// Round 5
// 1054.490 us; speedup vs baseline: 2.3863x; 2.3863x over previous
//
#include <hip/hip_runtime.h>
#include <hip/hip_fp16.h>
#include <cstdint>
#include <cstddef>

// GCNII: h0 = relu(x@W_in + b_in); 8x { s = .9*Ahat@h + .1*h0; h = relu(s @ Wl) };
// out = h@W_out + b_out.  Ahat = D^-1/2 (A + I) D^-1/2 (deg over targets, +1 self loop).
// Activations fp16; weights transposed+converted to fp16 once; MFMA f16 GEMMs (fp32 accum).
// CSR = 4B src only; norm recomputed as dinv[src]*dinv[dst] (wave-uniform broadcast loads).
// Aggregation kept standalone + LDS-free: it is latency-bound and needs max occupancy
// (round-4 fusion dropped occupancy 66%->17% and tripled layer time).

#define HID 128

using f16x8 = __attribute__((ext_vector_type(8))) _Float16;
using f32x4 = __attribute__((ext_vector_type(4))) float;

// ---------------- preprocessing ----------------

__global__ void k_hist(const int* __restrict__ col, int E, int* __restrict__ cnt) {
  int e = blockIdx.x * blockDim.x + threadIdx.x;
  if (e < E) atomicAdd(&cnt[col[e]], 1);
}

// block reduce of cnt -> bsum, plus dinv = rsqrt(cnt+1)
__global__ __launch_bounds__(256) void k_blocksum_dinv(const int* __restrict__ cnt,
                                                       int* __restrict__ bsum,
                                                       float* __restrict__ dinv, int N) {
  __shared__ int s[256];
  int t = threadIdx.x;
  int i = blockIdx.x * 256 + t;
  int v = (i < N) ? cnt[i] : 0;
  if (i < N) dinv[i] = rsqrtf((float)v + 1.0f);  // +1 self loop
  s[t] = v;
  __syncthreads();
  for (int off = 128; off > 0; off >>= 1) {
    if (t < off) s[t] += s[t + off];
    __syncthreads();
  }
  if (t == 0) bsum[blockIdx.x] = s[0];
}

__global__ __launch_bounds__(512) void k_scan_bsum(const int* __restrict__ bsum,
                                                   int* __restrict__ bofs, int nb) {
  __shared__ int s[512];
  __shared__ int carry;
  int t = threadIdx.x;
  if (t == 0) carry = 0;
  __syncthreads();
  for (int base = 0; base < nb; base += 512) {
    int i = base + t;
    int v = (i < nb) ? bsum[i] : 0;
    s[t] = v;
    __syncthreads();
    for (int off = 1; off < 512; off <<= 1) {
      int a = (t >= off) ? s[t - off] : 0;
      __syncthreads();
      s[t] += a;
      __syncthreads();
    }
    if (i < nb) bofs[i] = carry + s[t] - v;
    __syncthreads();
    if (t == 0) carry += s[511];
    __syncthreads();
  }
}

__global__ __launch_bounds__(256) void k_scan_write(const int* __restrict__ cnt,
                                                    const int* __restrict__ bofs,
                                                    int* __restrict__ row_ptr, int N) {
  __shared__ int s[256];
  int t = threadIdx.x;
  int i = blockIdx.x * 256 + t;
  int v = (i < N) ? cnt[i] : 0;
  s[t] = v;
  __syncthreads();
  for (int off = 1; off < 256; off <<= 1) {
    int a = (t >= off) ? s[t - off] : 0;
    __syncthreads();
    s[t] += a;
    __syncthreads();
  }
  int excl = bofs[blockIdx.x] + s[t] - v;
  if (i < N) row_ptr[i] = excl;
  if (i == N - 1) row_ptr[N] = excl + v;
}

__global__ void k_fill(const int* __restrict__ row, const int* __restrict__ col, int E,
                       const int* __restrict__ row_ptr, int* __restrict__ fill,
                       int* __restrict__ csr_src) {
  int e = blockIdx.x * blockDim.x + threadIdx.x;
  if (e >= E) return;
  int r = row[e], c = col[e];
  int p = row_ptr[c] + atomicAdd(&fill[c], 1);
  csr_src[p] = r;
}

// one-shot: transpose+fp16-convert all weight matrices.
// Wt layout: [L x (128x128)] [W_in (128x128)] [W_out (64x128)]; each stored [n][k].
__global__ void k_wprep(const float* __restrict__ Wc, const float* __restrict__ W_in,
                        const float* __restrict__ W_out, _Float16* __restrict__ Wt,
                        int L) {
  int id = blockIdx.x * blockDim.x + threadIdx.x;
  int nl = L * 16384;
  if (id < nl) {
    int l = id >> 14, r = id & 16383;
    int k = r >> 7, n = r & 127;
    Wt[(size_t)l * 16384 + n * 128 + k] = (_Float16)Wc[(size_t)l * 16384 + k * 128 + n];
  } else if (id < nl + 16384) {
    int r = id - nl;
    int k = r >> 7, n = r & 127;
    Wt[(size_t)nl + n * 128 + k] = (_Float16)W_in[k * 128 + n];
  } else if (id < nl + 16384 + 8192) {
    int r = id - nl - 16384;
    int k = r >> 6, n = r & 63;
    Wt[(size_t)(nl + 16384) + n * 128 + k] = (_Float16)W_out[k * 64 + n];
  }
}

__global__ void k_f2h(const float* __restrict__ src, _Float16* __restrict__ dst, int n) {
  int i = (blockIdx.x * blockDim.x + threadIdx.x) * 4;
  if (i < n) {
    float4 v = *(const float4*)(src + i);
    dst[i] = (_Float16)v.x;
    dst[i + 1] = (_Float16)v.y;
    dst[i + 2] = (_Float16)v.z;
    dst[i + 3] = (_Float16)v.w;
  }
}

// ---------------- aggregation (one wave per node, fp16 gather, atomic/LDS-free) --------

__global__ __launch_bounds__(256) void k_aggregate16(
    const _Float16* __restrict__ hp, const _Float16* __restrict__ x0h,
    const float* __restrict__ dinv, const int* __restrict__ row_ptr,
    const int* __restrict__ csr_src, _Float16* __restrict__ support, int N) {
  const __half* h = (const __half*)hp;
  int node = blockIdx.x * 4 + (threadIdx.x >> 6);
  if (node >= N) return;
  int lane = threadIdx.x & 63;
  int beg = row_ptr[node], end = row_ptr[node + 1];
  float di = dinv[node];
  // acc = di*h[node] + sum dinv[s]*h[s];  support = .9*di*acc + .1*x0
  float2 f0 = __half22float2(((const __half2*)(h + (size_t)node * HID))[lane]);
  float ax = di * f0.x;
  float ay = di * f0.y;
  int j = beg;
  for (; j + 4 <= end; j += 4) {
    int s0 = csr_src[j], s1 = csr_src[j + 1], s2 = csr_src[j + 2], s3 = csr_src[j + 3];
    float w0 = dinv[s0], w1 = dinv[s1], w2 = dinv[s2], w3 = dinv[s3];
    __half2 a0 = ((const __half2*)(h + (size_t)s0 * HID))[lane];
    __half2 a1 = ((const __half2*)(h + (size_t)s1 * HID))[lane];
    __half2 a2 = ((const __half2*)(h + (size_t)s2 * HID))[lane];
    __half2 a3 = ((const __half2*)(h + (size_t)s3 * HID))[lane];
    float2 f;
    f = __half22float2(a0); ax = fmaf(w0, f.x, ax); ay = fmaf(w0, f.y, ay);
    f = __half22float2(a1); ax = fmaf(w1, f.x, ax); ay = fmaf(w1, f.y, ay);
    f = __half22float2(a2); ax = fmaf(w2, f.x, ax); ay = fmaf(w2, f.y, ay);
    f = __half22float2(a3); ax = fmaf(w3, f.x, ax); ay = fmaf(w3, f.y, ay);
  }
  for (; j < end; ++j) {
    int s = csr_src[j];
    float w = dinv[s];
    float2 f = __half22float2(((const __half2*)(h + (size_t)s * HID))[lane]);
    ax = fmaf(w, f.x, ax);
    ay = fmaf(w, f.y, ay);
  }
  float2 xv = __half22float2(((const __half2*)((const __half*)x0h + (size_t)node * HID))[lane]);
  float s9 = 0.9f * di;
  float ox = s9 * ax + 0.1f * xv.x;
  float oy = s9 * ay + 0.1f * xv.y;
  ((__half2*)support)[(size_t)node * (HID / 2) + lane] = __floats2half2_rn(ox, oy);
}

// ---------------- MFMA GEMM: C[M][NC] = op(A[M][128] @ W),  Bt = W^T fp16 [NC][128] ----
// 256 threads = 4 waves; block tile 128 rows; wave: 32 rows = 2 m-tiles x NT n-tiles.
// Frag layouts (gfx950 16x16x32): A: row=lane&15, k=(lane>>4)*8+i (16B/lane);
// B via Bt: col=lane&15, k contiguous; C/D: col=lane&15, row=(lane>>4)*4+reg [m89].

template <int NC, bool RELU, bool BIAS, bool OHALF>
__global__ __launch_bounds__(256) void k_mfma_gemm(const _Float16* __restrict__ A,
                                                   const _Float16* __restrict__ Bt,
                                                   const float* __restrict__ bias,
                                                   void* __restrict__ Cv, int M) {
  constexpr int NT = NC / 16;
  int tid = threadIdx.x;
  int w = tid >> 6, l = tid & 63;
  int lm = l & 15, kg = l >> 4;
  int row0 = blockIdx.x * 128 + w * 32;

  f32x4 acc[2][NT];
#pragma unroll
  for (int mt = 0; mt < 2; ++mt)
#pragma unroll
    for (int nt = 0; nt < NT; ++nt) acc[mt][nt] = (f32x4){0.f, 0.f, 0.f, 0.f};

#pragma unroll
  for (int ks = 0; ks < 128; ks += 32) {
    f16x8 a0 = *(const f16x8*)(A + (size_t)(row0 + lm) * 128 + ks + kg * 8);
    f16x8 a1 = *(const f16x8*)(A + (size_t)(row0 + 16 + lm) * 128 + ks + kg * 8);
#pragma unroll
    for (int nt = 0; nt < NT; ++nt) {
      f16x8 b = *(const f16x8*)(Bt + (size_t)(nt * 16 + lm) * 128 + ks + kg * 8);
      acc[0][nt] = __builtin_amdgcn_mfma_f32_16x16x32_f16(a0, b, acc[0][nt], 0, 0, 0);
      acc[1][nt] = __builtin_amdgcn_mfma_f32_16x16x32_f16(a1, b, acc[1][nt], 0, 0, 0);
    }
  }

#pragma unroll
  for (int mt = 0; mt < 2; ++mt) {
#pragma unroll
    for (int nt = 0; nt < NT; ++nt) {
      int colc = nt * 16 + lm;
      float bv = BIAS ? bias[colc] : 0.0f;
#pragma unroll
      for (int i = 0; i < 4; ++i) {
        int r = row0 + mt * 16 + kg * 4 + i;
        if (r >= M) continue;
        float v = acc[mt][nt][i] + bv;
        if (RELU) v = fmaxf(v, 0.0f);
        if (OHALF)
          ((_Float16*)Cv)[(size_t)r * NC + colc] = (_Float16)v;
        else
          ((float*)Cv)[(size_t)r * NC + colc] = v;
      }
    }
  }
}

// ---------------- launch ----------------

extern "C" void kernel_launch(void* const* d_in, const int* in_sizes, int n_in,
                              void* d_out, int out_size, void* d_ws, size_t ws_size,
                              hipStream_t stream) {
  const float* x     = (const float*)d_in[0];
  const int*   ei    = (const int*)d_in[1];
  const float* W_in  = (const float*)d_in[2];
  const float* b_in  = (const float*)d_in[3];
  const float* Wc    = (const float*)d_in[4];
  const float* W_out = (const float*)d_in[5];
  const float* b_out = (const float*)d_in[6];
  float* out = (float*)d_out;

  const int N = in_sizes[0] / HID;          // 100000
  const int E = in_sizes[1] / 2;            // 1600000
  const int L = in_sizes[4] / (HID * HID);  // 8
  const int nb = (N + 255) / 256;           // scan blocks
  const int* row = ei;       // sources
  const int* col = ei + E;   // targets

  char* p = (char*)d_ws;
  auto alloc = [&](size_t bytes) {
    char* q = p;
    p += (bytes + 255) & ~(size_t)255;
    return q;
  };
  // fp16 activation buffers first so MFMA A-tile OOB reads (last partial block,
  // rows 100000..100095) land in adjacent ws, never past the allocation.
  _Float16* x0h   = (_Float16*)alloc((size_t)N * HID * 2);
  _Float16* sup16 = (_Float16*)alloc((size_t)N * HID * 2);   // also used as x-f16 staging
  _Float16* h16   = (_Float16*)alloc((size_t)N * HID * 2);
  _Float16* Wt    = (_Float16*)alloc((size_t)(L * 16384 + 16384 + 8192) * 2);
  int*    cnt     = (int*)alloc((size_t)N * 4);
  int*    row_ptr = (int*)alloc((size_t)(N + 1) * 4);
  int*    fill    = (int*)alloc((size_t)N * 4);
  int*    bsum    = (int*)alloc((size_t)nb * 4);
  int*    bofs    = (int*)alloc((size_t)nb * 4);
  float*  dinv    = (float*)alloc((size_t)N * 4);
  int*    csr_src = (int*)alloc((size_t)E * 4);
  (void)ws_size; (void)n_in; (void)out_size;

  const _Float16* Wt_in  = Wt + (size_t)L * 16384;
  const _Float16* Wt_out = Wt + (size_t)L * 16384 + 16384;

  hipMemsetAsync(cnt, 0, (size_t)N * 4, stream);
  hipMemsetAsync(fill, 0, (size_t)N * 4, stream);

  int nw = L * 16384 + 16384 + 8192;
  k_wprep<<<(nw + 255) / 256, 256, 0, stream>>>(Wc, W_in, W_out, Wt, L);
  k_hist<<<(E + 255) / 256, 256, 0, stream>>>(col, E, cnt);
  k_blocksum_dinv<<<nb, 256, 0, stream>>>(cnt, bsum, dinv, N);
  k_scan_bsum<<<1, 512, 0, stream>>>(bsum, bofs, nb);
  k_scan_write<<<nb, 256, 0, stream>>>(cnt, bofs, row_ptr, N);
  k_fill<<<(E + 255) / 256, 256, 0, stream>>>(row, col, E, row_ptr, fill, csr_src);

  int ggrid = (N + 127) / 128;  // 782
  // x -> f16 (staged in sup16), then input projection -> x0h
  k_f2h<<<(N * HID / 4 + 255) / 256, 256, 0, stream>>>(x, sup16, N * HID);
  k_mfma_gemm<128, true, true, true><<<ggrid, 256, 0, stream>>>(sup16, Wt_in, b_in,
                                                                x0h, N);

  const _Float16* hin = x0h;
  for (int l = 0; l < L; ++l) {
    k_aggregate16<<<(N + 3) / 4, 256, 0, stream>>>(hin, x0h, dinv, row_ptr, csr_src,
                                                   sup16, N);
    k_mfma_gemm<128, true, false, true><<<ggrid, 256, 0, stream>>>(
        sup16, Wt + (size_t)l * 16384, nullptr, h16, N);
    hin = h16;
  }
  // output projection (fp32 out)
  k_mfma_gemm<64, false, true, false><<<ggrid, 256, 0, stream>>>(hin, Wt_out, b_out,
                                                                 out, N);
}